// Round 3
// baseline (689.594 us; speedup 1.0000x reference)
//
#include <hip/hip_runtime.h>

// ImplicitResampleModule on MI355X (gfx950). DTYPE-ADAPTIVE round:
// a device-side probe on `offset` decides fp32 vs bf16 interpretation
// (deterministic per launch -> capture-safe). Canonicalization kernels
// normalize all inputs (offs->f32, W/b->bf16, feat->bf16 transposed),
// so the main fused kernel is single-path bf16 MFMA; only the final
// store branches on the probe.
//
// d_ws layout (use_t: ws >= 68,552,192 B):
//   [0, 64MB)            featT  u16 [B][HW][C]
//   [64MB, +1MB)         offsC  f32 [B*THW*2]
//   [+1MB, +128K ...)    WqC, WkC, WvC  u16[65536] each
//   [+1MB+384K, ...)     bqC, bkC, bvC  u16[256] each (512 B apart)
// If ws too small: canon at offset 0, no transpose (direct gather fallback).

using short8 = __attribute__((ext_vector_type(8))) short;   // 8 bf16
using f32x4  = __attribute__((ext_vector_type(4))) float;
typedef unsigned short u16;

#define LOG2_1E4 13.287712379549449f
#define TWO_PI   6.283185307179586f

__device__ __forceinline__ float bs2f(u16 s) {
    unsigned u = ((unsigned)s) << 16;
    float f; __builtin_memcpy(&f, &u, 4); return f;
}
__device__ __forceinline__ u16 f2bs(float f) {
    unsigned u; __builtin_memcpy(&u, &f, 4);
    u += 0x7fffu + ((u >> 16) & 1u);   // RNE
    return (u16)(u >> 16);
}

// Probe: bf16-decode offs at even u16 indices. True bf16 N(0,2) values are
// sane (|v| in [1e-3,1e3]) ~99.9%; fp32 mantissa-halves are insane ~92%.
// All waves read identical addresses -> block-uniform result.
__device__ __forceinline__ int probe_is_f32(const u16* offs_raw) {
    const int lane = threadIdx.x & 63;
    const float v = bs2f(offs_raw[lane * 2]);
    const float av = fabsf(v);
    const bool insane = !(av >= 1e-3f && av <= 1000.0f);   // NaN -> insane
    return __popcll(__ballot(insane)) >= 16 ? 1 : 0;
}

// ---------------- canonicalize offs / weights / biases ----------------
__global__ __launch_bounds__(256) void irm_canon(
    const void* offs_raw, const void* Wq_r, const void* bq_r,
    const void* Wk_r, const void* bk_r, const void* Wv_r, const void* bv_r,
    unsigned char* canon)
{
    const int is_f32 = probe_is_f32((const u16*)offs_raw);
    float* offsC = (float*)canon;
    u16* WqC = (u16*)(canon + (1u << 20));
    u16* WkC = (u16*)(canon + (1u << 20) + (1u << 17));
    u16* WvC = (u16*)(canon + (1u << 20) + (2u << 17));
    u16* bqC = (u16*)(canon + (1u << 20) + (3u << 17));
    u16* bkC = bqC + 256;
    u16* bvC = bkC + 256;

    const int gid = blockIdx.x * 256 + threadIdx.x;
    if (gid < 262144) {
        offsC[gid] = is_f32 ? ((const float*)offs_raw)[gid]
                            : bs2f(((const u16*)offs_raw)[gid]);
    } else if (gid < 262144 + 3 * 65536) {
        const int r = gid - 262144, w = r >> 16, i = r & 65535;
        const void* src = (w == 0) ? Wq_r : (w == 1) ? Wk_r : Wv_r;
        u16*       dst  = (w == 0) ? WqC  : (w == 1) ? WkC  : WvC;
        dst[i] = is_f32 ? f2bs(((const float*)src)[i]) : ((const u16*)src)[i];
    } else if (gid < 262144 + 3 * 65536 + 3 * 256) {
        const int r = gid - 262144 - 3 * 65536, w = r >> 8, i = r & 255;
        const void* src = (w == 0) ? bq_r : (w == 1) ? bk_r : bv_r;
        u16*       dst  = (w == 0) ? bqC  : (w == 1) ? bkC  : bvC;
        dst[i] = is_f32 ? f2bs(((const float*)src)[i]) : ((const u16*)src)[i];
    }
}

// ---------------- transpose feat [B,C,HW] -> featT bf16 [B,HW,C] ----------------
__global__ __launch_bounds__(256) void irm_transpose(const void* __restrict__ feat_raw,
                                                     const u16* __restrict__ offs_raw,
                                                     u16* __restrict__ featT) {
    const int is_f32 = probe_is_f32(offs_raw);
    __shared__ u16 tile[64][65];
    const int b   = blockIdx.z;
    const int c0  = blockIdx.y << 6;
    const int hw0 = blockIdx.x << 6;
    const int tid = threadIdx.x;
    const int r    = tid >> 4;          // 0..15
    const int col4 = (tid & 15) << 2;   // 0..60
    #pragma unroll
    for (int it = 0; it < 4; ++it) {
        const int c = (it << 4) + r;
        const size_t idx = ((size_t)((b << 8) + c0 + c) << 16) + hw0 + col4;
        if (is_f32) {
            float4 v = *(const float4*)((const float*)feat_raw + idx);
            tile[c][col4 + 0] = f2bs(v.x); tile[c][col4 + 1] = f2bs(v.y);
            tile[c][col4 + 2] = f2bs(v.z); tile[c][col4 + 3] = f2bs(v.w);
        } else {
            ushort4 v = *(const ushort4*)((const u16*)feat_raw + idx);
            tile[c][col4 + 0] = v.x; tile[c][col4 + 1] = v.y;
            tile[c][col4 + 2] = v.z; tile[c][col4 + 3] = v.w;
        }
    }
    __syncthreads();
    #pragma unroll
    for (int it = 0; it < 4; ++it) {
        const int hw = (it << 4) + r;
        ushort4 v;
        v.x = tile[col4 + 0][hw]; v.y = tile[col4 + 1][hw];
        v.z = tile[col4 + 2][hw]; v.w = tile[col4 + 3][hw];
        u16* dst = featT + ((size_t)((b << 16) + hw0 + hw) << 8) + c0 + col4;
        *(ushort4*)dst = v;
    }
}

// ---------------- main fused kernel ----------------
__global__ __launch_bounds__(256, 2) void irm_main(
    const void* __restrict__ fsrc,   // featT (bf16) if transposed else raw feat
    const int transposed,
    const u16* __restrict__ offs_raw,
    const float* __restrict__ offsC,
    const u16* __restrict__ Wq, const u16* __restrict__ bq,
    const u16* __restrict__ Wk, const u16* __restrict__ bk,
    const u16* __restrict__ Wv, const u16* __restrict__ bv,
    void* __restrict__ out_raw)
{
    const int is_f32 = probe_is_f32(offs_raw);

    __shared__ __align__(16) unsigned char smem[56832];
    float* posb = (float*)(smem);          // [4 u][256 c]
    u16*   sFw  = (u16*)(smem + 4096);     // [64 rows][264]
    u16*   sFb  = (u16*)(smem + 37888);    // [16 px][264]
    u16*   sQ   = (u16*)(smem + 46336);    // [16 px][264]
    float* sA   = (float*)(smem + 54784);  // [16 px][8 h][4 u]
    u16*   sK   = (u16*)(smem);            // [64 rows][264]  (phase 2)
    u16*   sV   = (u16*)(smem);            // [64 rows][264]  (phase 2b)

    const int tid = threadIdx.x;
    const int raw = blockIdx.x;
    const int wq_ = ((raw & 7) << 10) | (raw >> 3);   // XCD swizzle
    const int b   = wq_ >> 12;
    const int t0  = (wq_ & 4095) << 4;

    // ---- phase 0a: window-corner PE table (card = U-1 = 1) ----
    {
        const int c = tid;
        const int j = (c & 127) >> 1;
        const float invt = exp2f(-(float)j * (LOG2_1E4 / 64.0f));
        const float sc = TWO_PI / (1.0f + 1e-6f);
        #pragma unroll
        for (int u = 0; u < 4; ++u) {
            const float base = (c < 128) ? (float)(u >> 1) : (float)(u & 1);
            const float arg = base * sc * invt;
            posb[u * 256 + c] = (c & 1) ? __cosf(arg) : __sinf(arg);
        }
    }
    __syncthreads();

    // ---- phase 0b: gather + stage fw, fb ----
    {
        const int p  = tid >> 4;            // pixel 0..15
        const int cx = tid & 15;            // 16-channel group
        const int t  = t0 + p;
        const int ty = t >> 8, tx = t & 255;
        const float* op = offsC + (((size_t)b << 16) + (size_t)t) * 2;
        const float offx = op[0];           // offset[...,0] -> x  (ref's [::-1])
        const float offy = op[1];           // offset[...,1] -> y
        const float fy = (float)ty + offy;
        const float fx = (float)tx + offx;
        const float fiy = floorf(fy), fix = floorf(fx);
        const int iy = (int)fiy, ix = (int)fix;
        const float dy = fy - fiy, dx = fx - fix;

        float gsum[16];
        #pragma unroll
        for (int i = 0; i < 16; ++i) gsum[i] = 0.0f;

        #pragma unroll
        for (int u = 0; u < 4; ++u) {
            int hy = iy + (u >> 1); hy = hy < 0 ? 0 : (hy > 255 ? 255 : hy);
            int wx = ix + (u & 1);  wx = wx < 0 ? 0 : (wx > 255 ? 255 : wx);
            const int lin = (hy << 8) | wx;
            short8 g0, g1;
            if (transposed) {
                const u16* src = (const u16*)fsrc + (((size_t)(b << 16) + (size_t)lin) << 8) + (cx << 4);
                g0 = *(const short8*)(src);
                g1 = *(const short8*)(src + 8);
            } else {
                #pragma unroll
                for (int i = 0; i < 8; ++i) {
                    const size_t i0 = (((size_t)((b << 8) + (cx << 4) + i)) << 16) + lin;
                    const size_t i1 = (((size_t)((b << 8) + (cx << 4) + 8 + i)) << 16) + lin;
                    g0[i] = is_f32 ? (short)f2bs(((const float*)fsrc)[i0]) : (short)((const u16*)fsrc)[i0];
                    g1[i] = is_f32 ? (short)f2bs(((const float*)fsrc)[i1]) : (short)((const u16*)fsrc)[i1];
                }
            }
            short8 w0, w1;
            #pragma unroll
            for (int i = 0; i < 8; ++i) {
                const float f0 = bs2f((u16)g0[i]);
                const float f1 = bs2f((u16)g1[i]);
                gsum[i] += f0; gsum[i + 8] += f1;
                w0[i] = (short)f2bs(f0 + posb[u * 256 + (cx << 4) + i]);
                w1[i] = (short)f2bs(f1 + posb[u * 256 + (cx << 4) + 8 + i]);
            }
            *(short8*)&sFw[(p * 4 + u) * 264 + (cx << 4)]     = w0;
            *(short8*)&sFw[(p * 4 + u) * 264 + (cx << 4) + 8] = w1;
        }
        // fb = mean_u + PE(deci, card = 2)
        const float ys = dy * (TWO_PI / (2.0f + 1e-6f));
        const float xs = dx * (TWO_PI / (2.0f + 1e-6f));
        short8 q0, q1;
        #pragma unroll
        for (int i = 0; i < 16; ++i) {
            const int c = (cx << 4) + i;
            const int j = (c & 127) >> 1;
            const float invt = exp2f(-(float)j * (LOG2_1E4 / 64.0f));
            const float arg = ((c < 128) ? ys : xs) * invt;
            const float pe = (c & 1) ? __cosf(arg) : __sinf(arg);
            const float v = gsum[i] * 0.25f + pe;
            if (i < 8) q0[i] = (short)f2bs(v); else q1[i - 8] = (short)f2bs(v);
        }
        *(short8*)&sFb[p * 264 + (cx << 4)]     = q0;
        *(short8*)&sFb[p * 264 + (cx << 4) + 8] = q1;
    }
    __syncthreads();

    // ---- phase 1: projection GEMMs (MFMA), wave w owns cols [64w, 64w+64) ----
    const int lane = tid & 63;
    const int wv   = tid >> 6;
    const int c15  = lane & 15;
    const int qd   = lane >> 4;
    const int colbase = wv << 6;
    const f32x4 zero4 = {0.f, 0.f, 0.f, 0.f};

    f32x4 accK[4][4], accV[4][4];
    #pragma unroll
    for (int m = 0; m < 4; ++m)
        #pragma unroll
        for (int nt = 0; nt < 4; ++nt) { accK[m][nt] = zero4; accV[m][nt] = zero4; }

    // K = fw @ Wk^T
    #pragma unroll
    for (int ks = 0; ks < 8; ++ks) {
        short8 af[4], bfr[4];
        #pragma unroll
        for (int m = 0; m < 4; ++m)
            af[m] = *(const short8*)&sFw[(m * 16 + c15) * 264 + ks * 32 + qd * 8];
        #pragma unroll
        for (int nt = 0; nt < 4; ++nt)
            bfr[nt] = *(const short8*)&Wk[(colbase + nt * 16 + c15) * 256 + ks * 32 + qd * 8];
        #pragma unroll
        for (int m = 0; m < 4; ++m)
            #pragma unroll
            for (int nt = 0; nt < 4; ++nt)
                accK[m][nt] = __builtin_amdgcn_mfma_f32_16x16x32_bf16(af[m], bfr[nt], accK[m][nt], 0, 0, 0);
    }

    // Q = fb @ Wq^T (+bq) -> sQ (disjoint region; no barrier needed yet)
    {
        f32x4 accQ[4];
        #pragma unroll
        for (int nt = 0; nt < 4; ++nt) accQ[nt] = zero4;
        #pragma unroll
        for (int ks = 0; ks < 8; ++ks) {
            short8 aq = *(const short8*)&sFb[c15 * 264 + ks * 32 + qd * 8];
            #pragma unroll
            for (int nt = 0; nt < 4; ++nt) {
                short8 bw = *(const short8*)&Wq[(colbase + nt * 16 + c15) * 256 + ks * 32 + qd * 8];
                accQ[nt] = __builtin_amdgcn_mfma_f32_16x16x32_bf16(aq, bw, accQ[nt], 0, 0, 0);
            }
        }
        #pragma unroll
        for (int nt = 0; nt < 4; ++nt) {
            const int n = colbase + nt * 16 + c15;
            const float bias = bs2f(bq[n]);
            #pragma unroll
            for (int r = 0; r < 4; ++r)
                sQ[(qd * 4 + r) * 264 + n] = f2bs(accQ[nt][r] + bias);   // C: col=lane&15, row=qd*4+r
        }
    }

    // V = fw @ Wv^T (stays in registers)
    #pragma unroll
    for (int ks = 0; ks < 8; ++ks) {
        short8 af[4], bfr[4];
        #pragma unroll
        for (int m = 0; m < 4; ++m)
            af[m] = *(const short8*)&sFw[(m * 16 + c15) * 264 + ks * 32 + qd * 8];
        #pragma unroll
        for (int nt = 0; nt < 4; ++nt)
            bfr[nt] = *(const short8*)&Wv[(colbase + nt * 16 + c15) * 256 + ks * 32 + qd * 8];
        #pragma unroll
        for (int m = 0; m < 4; ++m)
            #pragma unroll
            for (int nt = 0; nt < 4; ++nt)
                accV[m][nt] = __builtin_amdgcn_mfma_f32_16x16x32_bf16(af[m], bfr[nt], accV[m][nt], 0, 0, 0);
    }

    __syncthreads();   // sFw/sFb/posb dead; sQ visible

    // ---- write sK (+bk), plain [row][264] ----
    #pragma unroll
    for (int nt = 0; nt < 4; ++nt) {
        const int n = colbase + nt * 16 + c15;
        const float bias = bs2f(bk[n]);
        #pragma unroll
        for (int m = 0; m < 4; ++m)
            #pragma unroll
            for (int r = 0; r < 4; ++r)
                sK[(m * 16 + qd * 4 + r) * 264 + n] = f2bs(accK[m][nt][r] + bias);
    }
    __syncthreads();   // sK visible

    // ---- logits + softmax: thread (p,h), threads 0..127 ----
    if (tid < 128) {
        const int p = tid & 15;
        const int h = tid >> 4;
        short8 q8[4];
        #pragma unroll
        for (int j = 0; j < 4; ++j)
            q8[j] = *(const short8*)&sQ[p * 264 + h * 32 + j * 8];
        float lg[4];
        #pragma unroll
        for (int u = 0; u < 4; ++u) {
            float acc = 0.0f;
            #pragma unroll
            for (int j = 0; j < 4; ++j) {
                short8 k8 = *(const short8*)&sK[(p * 4 + u) * 264 + h * 32 + j * 8];
                #pragma unroll
                for (int i = 0; i < 8; ++i)
                    acc += bs2f((u16)q8[j][i]) * bs2f((u16)k8[i]);
            }
            lg[u] = acc * 0.17677669529663687f;   // 32^-0.5
        }
        const float mx = fmaxf(fmaxf(lg[0], lg[1]), fmaxf(lg[2], lg[3]));
        float e[4], es = 0.0f;
        #pragma unroll
        for (int u = 0; u < 4; ++u) { e[u] = __expf(lg[u] - mx); es += e[u]; }
        const float inv = __fdividef(1.0f, es);
        #pragma unroll
        for (int u = 0; u < 4; ++u)
            sA[((p << 3) + h) * 4 + u] = e[u] * inv;
    }
    __syncthreads();   // logits done with sK; sA visible

    // ---- write sV (+bv), overlays sK ----
    #pragma unroll
    for (int nt = 0; nt < 4; ++nt) {
        const int n = colbase + nt * 16 + c15;
        const float bias = bs2f(bv[n]);
        #pragma unroll
        for (int m = 0; m < 4; ++m)
            #pragma unroll
            for (int r = 0; r < 4; ++r)
                sV[(m * 16 + qd * 4 + r) * 264 + n] = f2bs(accV[m][nt][r] + bias);
    }
    __syncthreads();   // sV visible

    // ---- PV + store: thread (p, h, dh) handles 16 output channels ----
    {
        const int p  = tid & 15;
        const int h  = (tid >> 4) & 7;
        const int dh = tid >> 7;
        float a4[4];
        #pragma unroll
        for (int u = 0; u < 4; ++u) a4[u] = sA[((p << 3) + h) * 4 + u];
        float acc[16];
        #pragma unroll
        for (int i = 0; i < 16; ++i) acc[i] = 0.0f;
        #pragma unroll
        for (int u = 0; u < 4; ++u) {
            const u16* vp = &sV[(p * 4 + u) * 264 + h * 32 + dh * 16];
            short8 v0 = *(const short8*)(vp);
            short8 v1 = *(const short8*)(vp + 8);
            #pragma unroll
            for (int i = 0; i < 8; ++i) {
                acc[i]     += a4[u] * bs2f((u16)v0[i]);
                acc[i + 8] += a4[u] * bs2f((u16)v1[i]);
            }
        }
        const size_t base = (((size_t)((b << 8) + h * 32 + dh * 16)) << 16) + t0 + p;
        if (is_f32) {
            float* dst = (float*)out_raw + base;
            #pragma unroll
            for (int i = 0; i < 16; ++i)
                dst[(size_t)i << 16] = acc[i];
        } else {
            u16* dst = (u16*)out_raw + base;
            #pragma unroll
            for (int i = 0; i < 16; ++i)
                dst[(size_t)i << 16] = f2bs(acc[i]);
        }
    }
}

extern "C" void kernel_launch(void* const* d_in, const int* in_sizes, int n_in,
                              void* d_out, int out_size, void* d_ws, size_t ws_size,
                              hipStream_t stream) {
    const size_t FEATT_BYTES = (size_t)1 << 26;   // 64 MB bf16 featT
    const size_t CANON_BYTES = (1u << 20) + (3u << 17) + 3 * 512;
    const int use_t = (ws_size >= FEATT_BYTES + CANON_BYTES) ? 1 : 0;   // ws_size constant -> capture-safe

    unsigned char* ws    = (unsigned char*)d_ws;
    unsigned char* canon = ws + (use_t ? FEATT_BYTES : 0);
    float* offsC = (float*)canon;
    u16* WqC = (u16*)(canon + (1u << 20));
    u16* WkC = (u16*)(canon + (1u << 20) + (1u << 17));
    u16* WvC = (u16*)(canon + (1u << 20) + (2u << 17));
    u16* bqC = (u16*)(canon + (1u << 20) + (3u << 17));
    u16* bkC = bqC + 256;
    u16* bvC = bkC + 256;

    irm_canon<<<1795, 256, 0, stream>>>(d_in[1], d_in[2], d_in[3], d_in[4],
                                        d_in[5], d_in[6], d_in[7], canon);
    if (use_t)
        irm_transpose<<<dim3(1024, 4, 2), 256, 0, stream>>>(d_in[0], (const u16*)d_in[1], (u16*)ws);
    irm_main<<<dim3(8192), 256, 0, stream>>>(use_t ? (const void*)ws : d_in[0], use_t,
                                             (const u16*)d_in[1], offsC,
                                             WqC, bqC, WkC, bkC, WvC, bvC, d_out);
}